// Round 1
// baseline (204.965 us; speedup 1.0000x reference)
//
#include <hip/hip_runtime.h>
#include <math.h>

#define BN   32
#define CN   256
#define HN   56
#define WN   56
#define HWN  (HN * WN)          // 3136
#define CHWN (CN * HWN)         // 802816
#define NPOS (BN * HWN)         // 100352
#define NTOT (BN * CHWN)        // 25690112

// Kernel 1: channel-wise mean and max per spatial position.
// One thread per (b,h,w). Lanes hit consecutive w -> coalesced 256B/wave/iter.
__global__ void sa_reduce_kernel(const float* __restrict__ x,
                                 float* __restrict__ avg,
                                 float* __restrict__ mx) {
    int p = blockIdx.x * blockDim.x + threadIdx.x;
    if (p >= NPOS) return;
    int b = p / HWN;
    int s = p - b * HWN;
    const float* xp = x + (size_t)b * CHWN + s;
    float sum = 0.0f;
    float m = -INFINITY;
#pragma unroll 8
    for (int c = 0; c < CN; ++c) {
        float v = xp[(size_t)c * HWN];
        sum += v;
        m = fmaxf(m, v);
    }
    avg[p] = sum * (1.0f / (float)CN);
    mx[p] = m;
}

// Kernel 2: 7x7 conv over the 2-channel (avg,max) map + sigmoid -> att map.
// Inputs are 0.8 MB -> L2-resident. Compute is trivial.
__global__ void sa_conv_kernel(const float* __restrict__ avg,
                               const float* __restrict__ mx,
                               const float* __restrict__ cw,
                               float* __restrict__ att) {
    int p = blockIdx.x * blockDim.x + threadIdx.x;
    if (p >= NPOS) return;
    int b = p / HWN;
    int s = p - b * HWN;
    int h = s / WN;
    int w = s - h * WN;
    const float* a0 = avg + b * HWN;
    const float* m0 = mx + b * HWN;
    float acc = 0.0f;
#pragma unroll
    for (int kh = 0; kh < 7; ++kh) {
        int hh = h + kh - 3;
        if (hh < 0 || hh >= HN) continue;
#pragma unroll
        for (int kw = 0; kw < 7; ++kw) {
            int ww = w + kw - 3;
            if (ww < 0 || ww >= WN) continue;
            int idx = hh * WN + ww;
            acc = fmaf(cw[kh * 7 + kw],      a0[idx], acc);
            acc = fmaf(cw[49 + kh * 7 + kw], m0[idx], acc);
        }
    }
    att[p] = 1.0f / (1.0f + expf(-acc));
}

// Kernel 3: out = x * att (broadcast over channels), float4 vectorized.
__global__ void sa_mul_kernel(const float4* __restrict__ x4,
                              const float* __restrict__ att,
                              float4* __restrict__ out4) {
    int i = blockIdx.x * blockDim.x + threadIdx.x;
    if (i >= NTOT / 4) return;
    int e = i * 4;                  // element index, < 2^31
    int b = e / CHWN;
    int s = e % HWN;                // position within spatial plane (mult of 4)
    const float4 a = *(const float4*)(att + b * HWN + s);
    float4 v = x4[i];
    v.x *= a.x;
    v.y *= a.y;
    v.z *= a.z;
    v.w *= a.w;
    out4[i] = v;
}

extern "C" void kernel_launch(void* const* d_in, const int* in_sizes, int n_in,
                              void* d_out, int out_size, void* d_ws, size_t ws_size,
                              hipStream_t stream) {
    const float* x  = (const float*)d_in[0];
    const float* cw = (const float*)d_in[1];
    float* out = (float*)d_out;

    float* avg = (float*)d_ws;
    float* mx  = avg + NPOS;
    float* att = mx + NPOS;

    {
        int threads = 256;
        int blocks = (NPOS + threads - 1) / threads;   // 392
        sa_reduce_kernel<<<blocks, threads, 0, stream>>>(x, avg, mx);
        sa_conv_kernel<<<blocks, threads, 0, stream>>>(avg, mx, cw, att);
    }
    {
        int n4 = NTOT / 4;                              // 6422528
        int threads = 256;
        int blocks = (n4 + threads - 1) / threads;      // 25088
        sa_mul_kernel<<<blocks, threads, 0, stream>>>((const float4*)x, att, (float4*)out);
    }
}